// Round 3
// baseline (997.476 us; speedup 1.0000x reference)
//
#include <hip/hip_runtime.h>

// ROI head: pool -> x@W1 relu -> @W2 relu -> @[W_loc|W_score]
// All heavy passes are HBM-streaming; every pass is arranged to walk memory
// LINEARLY (the only pattern measured at ~6.3 TB/s). fp32 weights are
// repacked once per launch into bf16 MFMA-fragment-ordered tiles
// [nt][ks][q][col][j]; the GEMM then reads 4KB-contiguous tiles per K-step,
// double-buffered through LDS (1 uint4 load + 1 ds_read_b128 per thread).

typedef short short8 __attribute__((ext_vector_type(8)));
typedef unsigned short ushort8 __attribute__((ext_vector_type(8)));
typedef float f32x4 __attribute__((ext_vector_type(4)));

__device__ __forceinline__ unsigned short bf16_rne(float f) {
    unsigned int u = __builtin_bit_cast(unsigned int, f);
    unsigned int r = (u + 0x7FFFu + ((u >> 16) & 1u)) >> 16;
    return (unsigned short)r;
}

// ---------------- transpose F[512][1900] -> FT[1900][512] -------------------
__global__ void transpose_kernel(const float* __restrict__ F,
                                 float* __restrict__ FT)
{
    __shared__ float t[32][33];
    const int xs = blockIdx.x * 32;   // spatial 0..1899
    const int cs = blockIdx.y * 32;   // channel 0..511
    const int tx = threadIdx.x, ty = threadIdx.y;  // 32 x 8
#pragma unroll
    for (int k = 0; k < 4; ++k) {
        int cc = cs + ty + k * 8;
        int xx = xs + tx;
        if (xx < 1900) t[ty + k * 8][tx] = F[cc * 1900 + xx];
    }
    __syncthreads();
#pragma unroll
    for (int k = 0; k < 4; ++k) {
        int xx = xs + ty + k * 8;
        int cc = cs + tx;
        if (xx < 1900) FT[xx * 512 + cc] = t[tx][ty + k * 8];
    }
}

// ---------------- pooling: FT[1900][512] -> X bf16 [128][25088] -------------
__global__ void pool_kernel(const float* __restrict__ FT,
                            const float* __restrict__ rois,
                            unsigned short* __restrict__ X)
{
    __shared__ unsigned short tile[256 * 49];
    const int r = blockIdx.x;
    const int c = blockIdx.y * 256 + threadIdx.x;   // channel
    const float4 rv = ((const float4*)rois)[r];
    const int y0 = (int)truncf(rv.x * 0.0625f);
    const int x0 = (int)truncf(rv.y * 0.0625f);
    const int y2 = (int)ceilf (rv.z * 0.0625f);
    const int x3 = (int)ceilf (rv.w * 0.0625f);
    const int Ly = y2 - y0, Lx = x3 - x0;

    int rb[7], re[7], cb[7], ce[7];
#pragma unroll
    for (int i = 0; i < 7; ++i) {
        rb[i] = y0 + (i * Ly) / 7;
        re[i] = min(min(y0 + ((i + 1) * Ly + 6) / 7, rb[i] + 7), 38);  // Kr cap
        cb[i] = x0 + (i * Lx) / 7;
        ce[i] = min(min(x0 + ((i + 1) * Lx + 6) / 7, cb[i] + 9), 50);  // Kc cap
    }

    int o = 0;
    for (int i = 0; i < 7; ++i) {
        for (int j = 0; j < 7; ++j) {
            float m = -3.4e38f;
            for (int rr = rb[i]; rr < re[i]; ++rr)
                for (int cc = cb[j]; cc < ce[j]; ++cc)
                    m = fmaxf(m, FT[(rr * 50 + cc) * 512 + c]);
            tile[threadIdx.x * 49 + o] = bf16_rne(m);
            ++o;
        }
    }
    __syncthreads();
    unsigned int* dst = (unsigned int*)(X + r * 25088 + blockIdx.y * (256 * 49));
    const unsigned int* src = (const unsigned int*)tile;
    for (int t = threadIdx.x; t < 256 * 49 / 2; t += 256) dst[t] = src[t];
}

// ---------------- repack W[K][4096] fp32 -> Wt bf16 tiles -------------------
// Wt layout: [nt=64][ks=KS][q=4][cl=64][j=8] shorts, tile = 4KB contiguous.
// value at (q,cl,j) = bf16(W[ks*32 + q*8 + j][nt*64 + cl]).
// One block per ks slab: reads 32 rows x 16KB linearly.
__global__ __launch_bounds__(256)
void repack_kernel(const float* __restrict__ W,
                   unsigned short* __restrict__ Wt, int KS)
{
    const int ks = blockIdx.x;
    const int t  = threadIdx.x;
    const int q  = t >> 6;                     // wave id = k-quad
    const float* src = W + (size_t)(ks * 32 + q * 8) * 4096;

    for (int tau = 0; tau < 16; ++tau) {
        const int cg = (t & 63) + 64 * tau;    // float4 group: cols 4cg..4cg+3
        float4 v[8];
#pragma unroll
        for (int j = 0; j < 8; ++j)
            v[j] = *(const float4*)(src + (size_t)j * 4096 + 4 * cg);
        const int col = 4 * cg;
        const int nt = col >> 6, cl = col & 63;
        unsigned short* dst = Wt + ((size_t)(nt * KS + ks) * 2048
                                    + (q * 64 + cl) * 8);
#pragma unroll
        for (int cc = 0; cc < 4; ++cc) {
            ushort8 o8;
#pragma unroll
            for (int j = 0; j < 8; ++j)
                o8[j] = bf16_rne(((const float*)&v[j])[cc]);
            *(ushort8*)(dst + cc * 8) = o8;
        }
    }
}

// ---------------- GEMM: P[sp] = A[128 x 32*slabs] * Wt-tiles ----------------
// grid (64 nt, S sp); 4 waves; wave w owns cols [bx*64+16w,+16), 128 rows.
// Per slab: block reads ONE contiguous 4KB tile (1 uint4/thread), LDS
// double-buffered; each lane's B-frag is one ds_read_b128.
template <int LDA>
__global__ __launch_bounds__(256, 4)
void gemm_tiled(const unsigned short* __restrict__ A,   // bf16 [128][LDA]
                const unsigned short* __restrict__ Wt,  // tiles
                float* __restrict__ P,                  // [S][128][4096]
                int KS, int slabs)
{
    __shared__ unsigned short lds[2][2048];
    constexpr int N = 4096;
    const int lane = threadIdx.x & 63;
    const int w    = threadIdx.x >> 6;
    const int q    = lane >> 4;
    const int m    = lane & 15;
    const int bx   = blockIdx.x;
    const int sp   = blockIdx.y;
    const int s0   = sp * slabs;

    const unsigned short* bt = Wt + (size_t)(bx * KS + s0) * 2048;
    const int toff    = threadIdx.x * 8;                 // shorts (16B/thread)
    const int ldsread = (q * 64 + w * 16 + m) * 8;       // shorts

    // preload slab 0
    *(uint4*)(&lds[0][toff]) = *(const uint4*)(bt + toff);
    __syncthreads();

    f32x4 acc[8] = {};
    const unsigned short* a_base = A + (size_t)m * LDA + (size_t)s0 * 32 + q * 8;

    for (int s = 0; s < slabs; ++s) {
        uint4 nv;
        const bool more = (s + 1 < slabs);
        if (more) nv = *(const uint4*)(bt + (size_t)(s + 1) * 2048 + toff);

        short8 bfrag = *(const short8*)(&lds[s & 1][ldsread]);
        short8 afrag[8];
#pragma unroll
        for (int t = 0; t < 8; ++t)
            afrag[t] = *(const short8*)(a_base + (size_t)t * 16 * LDA);
#pragma unroll
        for (int t = 0; t < 8; ++t)
            acc[t] = __builtin_amdgcn_mfma_f32_16x16x32_bf16(afrag[t], bfrag, acc[t], 0, 0, 0);
        a_base += 32;

        if (more) *(uint4*)(&lds[(s + 1) & 1][toff]) = nv;
        __syncthreads();
    }

    const int col = bx * 64 + w * 16 + m;
    float* p = P + (size_t)sp * 128 * N + col;
#pragma unroll
    for (int t = 0; t < 8; ++t)
#pragma unroll
        for (int r = 0; r < 4; ++r)
            p[(size_t)(16 * t + q * 4 + r) * N] = acc[t][r];
}

// ---------------- head GEMM: cols 0..83 -> W_loc, 84..104 -> W_score --------
__global__ __launch_bounds__(256, 4)
void gemm_head_kernel(const unsigned short* __restrict__ A,  // h2 bf16 [128][4096]
                      const float* __restrict__ Wl,          // [4096][84]
                      const float* __restrict__ Ws,          // [4096][21]
                      float* __restrict__ P,                 // [S][128][112]
                      int Kchunk)
{
    constexpr int LDA = 4096;
    const int lane = threadIdx.x & 63;
    const int w    = threadIdx.x >> 6;
    const int q    = lane >> 4;
    const int col  = blockIdx.x * 64 + w * 16 + (lane & 15);  // 0..127
    const int sp   = blockIdx.y;
    const int kbeg = sp * Kchunk;

    int stride; const float* bp;
    if (col < 84)       { stride = 84; bp = Wl + col; }
    else if (col < 105) { stride = 21; bp = Ws + (col - 84); }
    else                { stride = 0;  bp = Ws; }
    bp += (size_t)(kbeg + q * 8) * stride;

    f32x4 acc[8] = {};
    const unsigned short* a_base = A + (size_t)(lane & 15) * LDA + kbeg + q * 8;

    for (int ks = 0; ks < Kchunk; ks += 32) {
        short8 afrag[8];
#pragma unroll
        for (int t = 0; t < 8; ++t)
            afrag[t] = *(const short8*)(a_base + (size_t)t * 16 * LDA);
        short8 bfrag;
#pragma unroll
        for (int j = 0; j < 8; ++j)
            bfrag[j] = (short)bf16_rne(bp[(size_t)j * stride]);
#pragma unroll
        for (int t = 0; t < 8; ++t)
            acc[t] = __builtin_amdgcn_mfma_f32_16x16x32_bf16(afrag[t], bfrag, acc[t], 0, 0, 0);
        a_base += 32;
        bp += (size_t)32 * stride;
    }

    if (col < 112) {
        float* p = P + (size_t)sp * 128 * 112 + col;
#pragma unroll
        for (int t = 0; t < 8; ++t)
#pragma unroll
            for (int r = 0; r < 4; ++r)
                p[(size_t)(16 * t + q * 4 + r) * 112] = acc[t][r];
    }
}

// ---------------- split-K reduce + bias + relu -> bf16 ----------------------
__global__ void reduce_relu_kernel(const float* __restrict__ P,     // [16][128][4096]
                                   const float* __restrict__ bias,  // [4096]
                                   unsigned short* __restrict__ H)  // bf16 [128][4096]
{
    const int e = blockIdx.x * 256 + threadIdx.x;
    if (e >= 128 * 4096) return;
    constexpr int NT = 128 * 4096;
    float s = 0.f;
#pragma unroll
    for (int i = 0; i < 16; ++i) s += P[(size_t)i * NT + e];
    s += bias[e & 4095];
    s = fmaxf(s, 0.f);
    H[e] = bf16_rne(s);
}

// ---------------- head reduce + bias -> d_out (locs then scores) ------------
__global__ void reduce_head_kernel(const float* __restrict__ P,   // [64][128][112]
                                   const float* __restrict__ bl,  // [84]
                                   const float* __restrict__ bs,  // [21]
                                   float* __restrict__ out)       // 128*84 + 128*21
{
    const int e = blockIdx.x * 256 + threadIdx.x;
    if (e >= 128 * 112) return;
    const int m = e / 112, col = e % 112;
    if (col >= 105) return;
    float s = 0.f;
#pragma unroll
    for (int i = 0; i < 64; ++i) s += P[(size_t)i * 128 * 112 + e];
    if (col < 84) out[m * 84 + col] = s + bl[col];
    else          out[128 * 84 + m * 21 + (col - 84)] = s + bs[col - 84];
}

extern "C" void kernel_launch(void* const* d_in, const int* in_sizes, int n_in,
                              void* d_out, int out_size, void* d_ws, size_t ws_size,
                              hipStream_t stream)
{
    const float* feats = (const float*)d_in[0];
    const float* rois  = (const float*)d_in[1];
    const float* W1    = (const float*)d_in[2];
    const float* b1    = (const float*)d_in[3];
    const float* W2    = (const float*)d_in[4];
    const float* b2    = (const float*)d_in[5];
    const float* Wl    = (const float*)d_in[6];
    const float* bl    = (const float*)d_in[7];
    const float* Wsc   = (const float*)d_in[8];
    const float* bsc   = (const float*)d_in[9];
    float* out = (float*)d_out;

    char* ws = (char*)d_ws;
    unsigned short* X   = (unsigned short*)(ws);               //   6,422,528
    unsigned short* H1  = (unsigned short*)(ws + 6422528);     //   1,048,576
    unsigned short* H2  = (unsigned short*)(ws + 7471104);     //   1,048,576
    float* FT           = (float*)(ws + 8519680);              //   3,891,200
    unsigned short* Wt1 = (unsigned short*)(ws + 12410880);    // 205,520,896
    unsigned short* Wt2 = (unsigned short*)(ws + 217931776);   //  33,554,432
    float* P            = (float*)(ws + 251486208);            //  33,554,432

    transpose_kernel<<<dim3(60, 16), dim3(32, 8), 0, stream>>>(feats, FT);
    pool_kernel<<<dim3(128, 2), 256, 0, stream>>>(FT, rois, X);

    // W1: K=25088 -> 784 slabs; split-K 16 -> 49 slabs/block
    repack_kernel<<<784, 256, 0, stream>>>(W1, Wt1, 784);
    gemm_tiled<25088><<<dim3(64, 16), 256, 0, stream>>>(X, Wt1, P, 784, 49);
    reduce_relu_kernel<<<2048, 256, 0, stream>>>(P, b1, H1);

    // W2: K=4096 -> 128 slabs; split-K 16 -> 8 slabs/block
    repack_kernel<<<128, 256, 0, stream>>>(W2, Wt2, 128);
    gemm_tiled<4096><<<dim3(64, 16), 256, 0, stream>>>(H1, Wt2, P, 128, 8);
    reduce_relu_kernel<<<2048, 256, 0, stream>>>(P, b2, H2);

    // head: K=4096, split 64 -> Kchunk 64
    gemm_head_kernel<<<dim3(2, 64), 256, 0, stream>>>(H2, Wl, Wsc, P, 64);
    reduce_head_kernel<<<56, 256, 0, stream>>>(P, bl, bsc, out);
}